// Round 7
// baseline (588.052 us; speedup 1.0000x reference)
//
#include <hip/hip_runtime.h>
#include <hip/hip_bf16.h>
#include <cfloat>

#define NTOK 4096
#define D_ 1024
#define DICT_ 16384
#define TOPK 8
#define NCAND 12
#define NBLK 64          // gemm col-blocks per token row (DICT_/256)
#define CPB 6            // candidates kept per (token, col-block)
#define LN_EPS 1e-5f

typedef __attribute__((ext_vector_type(8))) short bf16x8;
typedef __attribute__((ext_vector_type(4))) float f32x4;
typedef __attribute__((ext_vector_type(4))) unsigned short us4;

__device__ __forceinline__ unsigned short f2bf(float f) {
    unsigned int u = __float_as_uint(f);
    u += 0x7fffu + ((u >> 16) & 1u);   // RNE
    return (unsigned short)(u >> 16);
}

__device__ __forceinline__ void gl2lds16(const void* gsrc, void* ldsdst) {
    __builtin_amdgcn_global_load_lds(
        (const __attribute__((address_space(1))) unsigned int*)gsrc,
        (__attribute__((address_space(3))) unsigned int*)ldsdst, 16, 0, 0);
}

// ---------------- K1: LayerNorm -> bf16 normed ----------------
__global__ __launch_bounds__(256) void ln_kernel(const float* __restrict__ x,
                                                 const float* __restrict__ gamma,
                                                 const float* __restrict__ beta,
                                                 unsigned short* __restrict__ nb) {
    int t = blockIdx.x;
    int tid = threadIdx.x;
    const float4 v = ((const float4*)(x + (size_t)t * D_))[tid];

    float s = v.x + v.y + v.z + v.w;
    #pragma unroll
    for (int off = 32; off > 0; off >>= 1) s += __shfl_down(s, off, 64);
    __shared__ float red[4];
    int wid = tid >> 6, lane = tid & 63;
    if (lane == 0) red[wid] = s;
    __syncthreads();
    float mu = (red[0] + red[1] + red[2] + red[3]) * (1.0f / D_);
    __syncthreads();

    float dx = v.x - mu, dy = v.y - mu, dz = v.z - mu, dw = v.w - mu;
    float ss = dx * dx + dy * dy + dz * dz + dw * dw;
    #pragma unroll
    for (int off = 32; off > 0; off >>= 1) ss += __shfl_down(ss, off, 64);
    if (lane == 0) red[wid] = ss;
    __syncthreads();
    float var = (red[0] + red[1] + red[2] + red[3]) * (1.0f / D_);
    float rs = rsqrtf(var + LN_EPS);

    const float4 g = ((const float4*)gamma)[tid];
    const float4 b = ((const float4*)beta)[tid];
    us4 o;
    o.x = f2bf(dx * rs * g.x + b.x);
    o.y = f2bf(dy * rs * g.y + b.y);
    o.z = f2bf(dz * rs * g.z + b.z);
    o.w = f2bf(dw * rs * g.w + b.w);
    ((us4*)(nb + (size_t)t * D_))[tid] = o;
}

// ---------------- K1b: W_enc fp32 -> bf16 ----------------
__global__ __launch_bounds__(256) void cvt_kernel(const float* __restrict__ W,
                                                  unsigned short* __restrict__ Wb) {
    const int tid = threadIdx.x;
    const size_t base = (size_t)blockIdx.x * 1024;
    #pragma unroll
    for (int j = 0; j < 4; j++) {
        size_t i = base + j * 256 + tid;
        float4 f = ((const float4*)W)[i];
        us4 o;
        o.x = f2bf(f.x); o.y = f2bf(f.y); o.z = f2bf(f.z); o.w = f2bf(f.w);
        ((us4*)Wb)[i] = o;
    }
}

// ---------------- K2: 256x256 bf16 MFMA GEMM + fused per-row top-6 candidates ----------------
// 512 threads = 8 waves (2M x 4N). Wave tile 128x64 (8x4 16x16 frags). BK=64.
// LDS: 2 buffers x (A 256x64 + B 256x64) bf16 = 128 KiB, 3-bit XOR swizzle.
// Epilogue reuses the LDS to stage fp32 C-quadrants and select per-token top-6
// candidates per 256-col block (no logits array is ever written to global).
__global__ __launch_bounds__(512, 1) void gemm_kernel(const unsigned short* __restrict__ A,
                                                      const unsigned short* __restrict__ B,
                                                      float* __restrict__ cbv,
                                                      int* __restrict__ cbi) {
    __shared__ unsigned short lds[2][2][256][64];
    const int tid = threadIdx.x;
    const int lane = tid & 63;
    const int w = tid >> 6;
    const int wm = w >> 2, wn = w & 3;
    const int col0 = blockIdx.x * 256;   // dict cols
    const int row0 = blockIdx.y * 256;   // token rows

    f32x4 acc[8][4] = {};

    // stage one 128-row half (16KB = 1024 chunks of 16B): 2 chunks/thread.
    auto stage = [&](int b, int mat, const unsigned short* __restrict__ G,
                     int rbase, int k0, int h) {
        unsigned short* plane = &lds[b][mat][0][0];
        #pragma unroll
        for (int i = 0; i < 2; i++) {
            const int cb = h * 1024 + i * 512 + w * 64;   // wave-uniform chunk base
            const int c = cb + lane;
            const int r = c >> 3, sl = c & 7, g = sl ^ (r & 7);
            gl2lds16(G + (size_t)(rbase + r) * 1024 + k0 + g * 8, plane + (size_t)cb * 8);
        }
    };

    // prologue: stage tile 0 into buf 0
    stage(0, 0, A, row0, 0, 0);
    stage(0, 0, A, row0, 0, 1);
    stage(0, 1, B, col0, 0, 0);
    stage(0, 1, B, col0, 0, 1);

    const int arow = wm * 128 + (lane & 15);
    const int brow = wn * 64 + (lane & 15);
    const int kg = lane >> 4;

    for (int t = 0; t < 16; t++) {
        const int cur = t & 1, nxt = cur ^ 1;
        const int kn = ((t + 1) & 15) * 64;   // wrap-around keeps loop uniform

        // ---- phase 0: issue next A halves; wait tile t (leave 4 in flight); kk0, n={0,1}
        stage(nxt, 0, A, row0, kn, 0);
        stage(nxt, 0, A, row0, kn, 1);
        asm volatile("s_waitcnt vmcnt(4)" ::: "memory");
        __builtin_amdgcn_s_barrier();
        __builtin_amdgcn_sched_barrier(0);
        asm volatile("" ::: "memory");

        bf16x8 af[8];
        #pragma unroll
        for (int m = 0; m < 8; m++) {
            const int r = arow + m * 16;
            af[m] = *(const bf16x8*)&lds[cur][0][r][(kg ^ (r & 7)) * 8];
        }
        bf16x8 b0, b1;
        { const int r = brow;      b0 = *(const bf16x8*)&lds[cur][1][r][(kg ^ (r & 7)) * 8]; }
        { const int r = brow + 16; b1 = *(const bf16x8*)&lds[cur][1][r][(kg ^ (r & 7)) * 8]; }
        __builtin_amdgcn_s_setprio(1);
        #pragma unroll
        for (int m = 0; m < 8; m++) {
            acc[m][0] = __builtin_amdgcn_mfma_f32_16x16x32_bf16(af[m], b0, acc[m][0], 0, 0, 0);
            acc[m][1] = __builtin_amdgcn_mfma_f32_16x16x32_bf16(af[m], b1, acc[m][1], 0, 0, 0);
        }
        __builtin_amdgcn_s_setprio(0);

        // ---- phase 1: issue next B halves; kk0, n={2,3}
        stage(nxt, 1, B, col0, kn, 0);
        stage(nxt, 1, B, col0, kn, 1);
        { const int r = brow + 32; b0 = *(const bf16x8*)&lds[cur][1][r][(kg ^ (r & 7)) * 8]; }
        { const int r = brow + 48; b1 = *(const bf16x8*)&lds[cur][1][r][(kg ^ (r & 7)) * 8]; }
        __builtin_amdgcn_s_setprio(1);
        #pragma unroll
        for (int m = 0; m < 8; m++) {
            acc[m][2] = __builtin_amdgcn_mfma_f32_16x16x32_bf16(af[m], b0, acc[m][2], 0, 0, 0);
            acc[m][3] = __builtin_amdgcn_mfma_f32_16x16x32_bf16(af[m], b1, acc[m][3], 0, 0, 0);
        }
        __builtin_amdgcn_s_setprio(0);

        // ---- phase 2: kk1, n={0,1}
        #pragma unroll
        for (int m = 0; m < 8; m++) {
            const int r = arow + m * 16;
            af[m] = *(const bf16x8*)&lds[cur][0][r][((4 + kg) ^ (r & 7)) * 8];
        }
        { const int r = brow;      b0 = *(const bf16x8*)&lds[cur][1][r][((4 + kg) ^ (r & 7)) * 8]; }
        { const int r = brow + 16; b1 = *(const bf16x8*)&lds[cur][1][r][((4 + kg) ^ (r & 7)) * 8]; }
        __builtin_amdgcn_s_setprio(1);
        #pragma unroll
        for (int m = 0; m < 8; m++) {
            acc[m][0] = __builtin_amdgcn_mfma_f32_16x16x32_bf16(af[m], b0, acc[m][0], 0, 0, 0);
            acc[m][1] = __builtin_amdgcn_mfma_f32_16x16x32_bf16(af[m], b1, acc[m][1], 0, 0, 0);
        }
        __builtin_amdgcn_s_setprio(0);

        // ---- phase 3: kk1, n={2,3}
        { const int r = brow + 32; b0 = *(const bf16x8*)&lds[cur][1][r][((4 + kg) ^ (r & 7)) * 8]; }
        { const int r = brow + 48; b1 = *(const bf16x8*)&lds[cur][1][r][((4 + kg) ^ (r & 7)) * 8]; }
        __builtin_amdgcn_s_setprio(1);
        #pragma unroll
        for (int m = 0; m < 8; m++) {
            acc[m][2] = __builtin_amdgcn_mfma_f32_16x16x32_bf16(af[m], b0, acc[m][2], 0, 0, 0);
            acc[m][3] = __builtin_amdgcn_mfma_f32_16x16x32_bf16(af[m], b1, acc[m][3], 0, 0, 0);
        }
        __builtin_amdgcn_s_setprio(0);

        __builtin_amdgcn_s_barrier();
        __builtin_amdgcn_sched_barrier(0);
        asm volatile("" ::: "memory");
    }

    // ---- epilogue: drain in-flight wrap-around DMA before reusing LDS! ----
    asm volatile("s_waitcnt vmcnt(0)" ::: "memory");
    __builtin_amdgcn_s_barrier();
    __builtin_amdgcn_sched_barrier(0);

    // LDS reuse: sf = [64][260] f32 staging (padded rows), mv/mi = [64][49] merge scratch
    float* sf = (float*)&lds[0][0][0][0];
    float* mv = sf + 64 * 260;            // 16640 floats
    int*   mi = (int*)(mv + 64 * 49);     // +3136
    // total 22912 floats = 91.6 KB < 128 KB

    #pragma unroll 1
    for (int p = 0; p < 4; p++) {
        // stage 64-row quadrant p (rows p*64 .. p*64+63) as fp32
        if (wm == (p >> 1)) {
            const int mb = (p & 1) * 4;
            #pragma unroll
            for (int mm = 0; mm < 4; mm++) {
                #pragma unroll
                for (int n = 0; n < 4; n++) {
                    #pragma unroll
                    for (int r = 0; r < 4; r++) {
                        const int lrow = mm * 16 + (lane >> 4) * 4 + r;
                        sf[lrow * 260 + wn * 64 + n * 16 + (lane & 15)] = acc[mb + mm][n][r];
                    }
                }
            }
        }
        __syncthreads();

        // scan: 8 threads per row, stride-8 columns, per-thread top-6 insertion list
        {
            const int lr = tid >> 3, c8 = tid & 7;
            float v[CPB]; int id[CPB];
            #pragma unroll
            for (int j = 0; j < CPB; j++) { v[j] = -FLT_MAX; id[j] = -1; }
            #pragma unroll 4
            for (int k = 0; k < 32; k++) {
                const int col = c8 + k * 8;
                const float f = sf[lr * 260 + col];
                if (f > v[CPB - 1]) {
                    v[CPB - 1] = f; id[CPB - 1] = col0 + col;
                    #pragma unroll
                    for (int q = CPB - 1; q > 0; q--) {
                        if (v[q] > v[q - 1]) {
                            float tf = v[q]; v[q] = v[q - 1]; v[q - 1] = tf;
                            int ti = id[q]; id[q] = id[q - 1]; id[q - 1] = ti;
                        }
                    }
                }
            }
            const int mb2 = lr * 49 + c8 * CPB;
            #pragma unroll
            for (int j = 0; j < CPB; j++) { mv[mb2 + j] = v[j]; mi[mb2 + j] = id[j]; }
        }
        __syncthreads();

        // merge 48 -> top-6 per row; write candidates
        if (tid < 64) {
            float v[CPB]; int id[CPB];
            #pragma unroll
            for (int j = 0; j < CPB; j++) { v[j] = -FLT_MAX; id[j] = -1; }
            #pragma unroll 1
            for (int s = 0; s < 48; s++) {
                const float f = mv[tid * 49 + s];
                const int ii = mi[tid * 49 + s];
                if (f > v[CPB - 1]) {
                    v[CPB - 1] = f; id[CPB - 1] = ii;
                    #pragma unroll
                    for (int q = CPB - 1; q > 0; q--) {
                        if (v[q] > v[q - 1]) {
                            float tf = v[q]; v[q] = v[q - 1]; v[q - 1] = tf;
                            int ti = id[q]; id[q] = id[q - 1]; id[q - 1] = ti;
                        }
                    }
                }
            }
            const int token = row0 + p * 64 + tid;
            const size_t cb = ((size_t)token * NBLK + blockIdx.x) * CPB;
            #pragma unroll
            for (int j = 0; j < CPB; j++) { cbv[cb + j] = v[j]; cbi[cb + j] = id[j]; }
        }
        __syncthreads();
    }
}

// ---------------- K3: merge 64x6 block candidates -> top-12 per token ----------------
__global__ __launch_bounds__(256) void cand_merge_kernel(const float* __restrict__ cbv,
                                                         const int* __restrict__ cbi,
                                                         int* __restrict__ cand) {
    const int token = blockIdx.x;
    const int tid = threadIdx.x;
    const size_t base = (size_t)token * (NBLK * CPB);   // 384 items

    float a0 = cbv[base + tid];
    int j0 = cbi[base + tid];
    float a1 = -FLT_MAX;
    int j1 = -1;
    if (tid < 128) {
        a1 = cbv[base + 256 + tid];
        j1 = cbi[base + 256 + tid];
        if (a1 > a0) { float tf = a0; a0 = a1; a1 = tf; int ti = j0; j0 = j1; j1 = ti; }
    }

    __shared__ float hv[256];
    __shared__ int hi[256];
    __shared__ int wt;
    hv[tid] = a0;
    hi[tid] = j0;
    int myp = 0;

    for (int round = 0; round < NCAND; round++) {
        __syncthreads();
        if (tid < 64) {
            float bv = hv[tid]; int bt = tid;
            #pragma unroll
            for (int q = 1; q < 4; q++) {
                const int t2 = tid + q * 64;
                const float v2 = hv[t2];
                if (v2 > bv || (v2 == bv && t2 < bt)) { bv = v2; bt = t2; }
            }
            #pragma unroll
            for (int off = 32; off > 0; off >>= 1) {
                const float ov = __shfl_down(bv, off, 64);
                const int ot = __shfl_down(bt, off, 64);
                if (ov > bv || (ov == bv && ot < bt)) { bv = ov; bt = ot; }
            }
            if (tid == 0) wt = bt;
        }
        __syncthreads();
        if (tid == wt) {
            cand[(size_t)token * NCAND + round] = hi[tid];
            myp++;
            if (myp == 1) { hv[tid] = a1; hi[tid] = j1; }
            else { hv[tid] = -FLT_MAX; hi[tid] = -1; }
        }
    }
}

// ---------------- K4: exact fp32 refine of 12 candidates -> top-8 sel ----------------
__global__ __launch_bounds__(256) void refine_kernel(const float* __restrict__ x,
                                                     const float* __restrict__ gamma,
                                                     const float* __restrict__ beta,
                                                     const float* __restrict__ Wenc,
                                                     const int* __restrict__ cand,
                                                     float* __restrict__ sel_val,
                                                     int* __restrict__ sel_idx) {
    const int token = blockIdx.x;
    const int tid = threadIdx.x;
    const int lane = tid & 63;
    const int w = tid >> 6;

    __shared__ float red[4];
    __shared__ float ln[D_];

    const float4 v = ((const float4*)(x + (size_t)token * D_))[tid];
    float s = v.x + v.y + v.z + v.w;
    #pragma unroll
    for (int off = 32; off > 0; off >>= 1) s += __shfl_down(s, off, 64);
    if (lane == 0) red[w] = s;
    __syncthreads();
    float mu = (red[0] + red[1] + red[2] + red[3]) * (1.0f / D_);
    __syncthreads();
    float dx = v.x - mu, dy = v.y - mu, dz = v.z - mu, dw = v.w - mu;
    float ss = dx * dx + dy * dy + dz * dz + dw * dw;
    #pragma unroll
    for (int off = 32; off > 0; off >>= 1) ss += __shfl_down(ss, off, 64);
    if (lane == 0) red[w] = ss;
    __syncthreads();
    float var = (red[0] + red[1] + red[2] + red[3]) * (1.0f / D_);
    float rs = rsqrtf(var + LN_EPS);
    const float4 g = ((const float4*)gamma)[tid];
    const float4 b = ((const float4*)beta)[tid];
    float4 o;
    o.x = dx * rs * g.x + b.x;
    o.y = dy * rs * g.y + b.y;
    o.z = dz * rs * g.z + b.z;
    o.w = dw * rs * g.w + b.w;
    ((float4*)ln)[tid] = o;
    __syncthreads();

    __shared__ float dv[NCAND];
    __shared__ int di_s[NCAND];
    for (int c = w; c < NCAND; c += 4) {
        const int di = cand[(size_t)token * NCAND + c];
        const float4* wr = (const float4*)(Wenc + (size_t)di * D_);
        float acc = 0.f;
        #pragma unroll
        for (int j = 0; j < 4; j++) {
            const float4 q = wr[j * 64 + lane];
            const float4 p = ((const float4*)ln)[j * 64 + lane];
            acc += q.x * p.x + q.y * p.y + q.z * p.z + q.w * p.w;
        }
        #pragma unroll
        for (int off = 32; off > 0; off >>= 1) acc += __shfl_down(acc, off, 64);
        if (lane == 0) { dv[c] = acc; di_s[c] = di; }
    }
    __syncthreads();

    __shared__ float wv[TOPK];
    __shared__ int wi[TOPK];
    if (tid == 0) {
        unsigned int used = 0;
        for (int p = 0; p < TOPK; p++) {
            float bv = -FLT_MAX; int bc = -1;
            for (int c = 0; c < NCAND; c++) {
                if (used & (1u << c)) continue;
                const float cv = dv[c];
                if (cv > bv || (cv == bv && di_s[c] < ((bc >= 0) ? di_s[bc] : 0x7fffffff))) { bv = cv; bc = c; }
            }
            used |= 1u << bc;
            wv[p] = dv[bc]; wi[p] = di_s[bc];
        }
    }
    __syncthreads();
    if (tid < TOPK) {
        sel_val[(size_t)token * TOPK + tid] = wv[tid];
        sel_idx[(size_t)token * TOPK + tid] = wi[tid];
    }
}

// ---------------- K5: fused sparse-row writer + reconstruction ----------------
// One block per token: issue the 8 Wdict row loads, stream the full 16384-float
// sparse row (zeros + 8 patched) with NT stores, then FMA the recon and store.
__global__ __launch_bounds__(256) void sparse_recon_kernel(const float* __restrict__ sel_val,
                                                           const int* __restrict__ sel_idx,
                                                           const float* __restrict__ Wdict,
                                                           float* __restrict__ sparse,
                                                           float* __restrict__ recon) {
    const int token = blockIdx.x;
    const int tid = threadIdx.x;
    __shared__ float v8[TOPK];
    __shared__ int i8[TOPK];
    if (tid < TOPK) {
        v8[tid] = sel_val[(size_t)token * TOPK + tid];
        i8[tid] = sel_idx[(size_t)token * TOPK + tid];
    }
    __syncthreads();

    // issue recon loads early (latency hides under the store stream)
    float4 wr[TOPK];
    #pragma unroll
    for (int j = 0; j < TOPK; j++)
        wr[j] = ((const float4*)(Wdict + (size_t)i8[j] * D_))[tid];

    f32x4* row = (f32x4*)(sparse + (size_t)token * DICT_);
    #pragma unroll
    for (int q = 0; q < 16; q++) {
        const int grp = q * 256 + tid;       // 4096 groups: full row
        const int base = grp * 4;
        f32x4 o = {0.f, 0.f, 0.f, 0.f};
        #pragma unroll
        for (int j = 0; j < TOPK; j++) {
            const int rel = i8[j] - base;
            o.x = (rel == 0) ? v8[j] : o.x;
            o.y = (rel == 1) ? v8[j] : o.y;
            o.z = (rel == 2) ? v8[j] : o.z;
            o.w = (rel == 3) ? v8[j] : o.w;
        }
        __builtin_nontemporal_store(o, row + grp);
    }

    float4 acc = {0.f, 0.f, 0.f, 0.f};
    #pragma unroll
    for (int j = 0; j < TOPK; j++) {
        const float c = v8[j];
        acc.x = fmaf(c, wr[j].x, acc.x);
        acc.y = fmaf(c, wr[j].y, acc.y);
        acc.z = fmaf(c, wr[j].z, acc.z);
        acc.w = fmaf(c, wr[j].w, acc.w);
    }
    ((float4*)(recon + (size_t)token * D_))[tid] = acc;
}

extern "C" void kernel_launch(void* const* d_in, const int* in_sizes, int n_in,
                              void* d_out, int out_size, void* d_ws, size_t ws_size,
                              hipStream_t stream) {
    const float* x = (const float*)d_in[0];
    const float* gamma = (const float*)d_in[1];
    const float* beta = (const float*)d_in[2];
    const float* Wenc = (const float*)d_in[3];
    const float* Wdict = (const float*)d_in[4];

    float* recon = (float*)d_out;
    float* sparse = (float*)d_out + (size_t)NTOK * D_;

    // scratch in d_ws (~55 MB)
    unsigned short* We = (unsigned short*)d_ws;                   // bf16 W_enc, 33.5 MB
    unsigned short* Nb = We + (size_t)DICT_ * D_;                 // bf16 normed, 8 MB
    float* cbv = (float*)(Nb + (size_t)NTOK * D_);                // 4096*64*6 f32
    int* cbi = (int*)(cbv + (size_t)NTOK * NBLK * CPB);           // 4096*64*6 int
    int* cand = cbi + (size_t)NTOK * NBLK * CPB;                  // 4096*12 int
    float* sel_val = (float*)(cand + (size_t)NTOK * NCAND);       // 4096*8 f32
    int* sel_idx = (int*)(sel_val + (size_t)NTOK * TOPK);         // 4096*8 int

    ln_kernel<<<NTOK, 256, 0, stream>>>(x, gamma, beta, Nb);
    cvt_kernel<<<DICT_ * D_ / 4096, 256, 0, stream>>>(Wenc, We);

    dim3 gg(DICT_ / 256, NTOK / 256);
    gemm_kernel<<<gg, 512, 0, stream>>>(Nb, We, cbv, cbi);

    cand_merge_kernel<<<NTOK, 256, 0, stream>>>(cbv, cbi, cand);

    refine_kernel<<<NTOK, 256, 0, stream>>>(x, gamma, beta, Wenc, cand,
                                            sel_val, sel_idx);

    sparse_recon_kernel<<<NTOK, 256, 0, stream>>>(sel_val, sel_idx, Wdict,
                                                  sparse, recon);
}

// Round 8
// 449.048 us; speedup vs baseline: 1.3096x; 1.3096x over previous
//
#include <hip/hip_runtime.h>
#include <hip/hip_bf16.h>
#include <cfloat>

#define NTOK 4096
#define D_ 1024
#define DICT_ 16384
#define TOPK 8
#define NCAND 12
#define NBLK 64          // gemm col-blocks per token row (DICT_/256)
#define CPB 6            // candidates kept per (token, col-block)
#define LN_EPS 1e-5f

typedef __attribute__((ext_vector_type(8))) short bf16x8;
typedef __attribute__((ext_vector_type(4))) float f32x4;
typedef __attribute__((ext_vector_type(4))) unsigned short us4;

__device__ __forceinline__ unsigned short f2bf(float f) {
    unsigned int u = __float_as_uint(f);
    u += 0x7fffu + ((u >> 16) & 1u);   // RNE
    return (unsigned short)(u >> 16);
}

__device__ __forceinline__ void gl2lds16(const void* gsrc, void* ldsdst) {
    __builtin_amdgcn_global_load_lds(
        (const __attribute__((address_space(1))) unsigned int*)gsrc,
        (__attribute__((address_space(3))) unsigned int*)ldsdst, 16, 0, 0);
}

// ---------------- K1: LayerNorm -> bf16 normed ----------------
__global__ __launch_bounds__(256) void ln_kernel(const float* __restrict__ x,
                                                 const float* __restrict__ gamma,
                                                 const float* __restrict__ beta,
                                                 unsigned short* __restrict__ nb) {
    int t = blockIdx.x;
    int tid = threadIdx.x;
    const float4 v = ((const float4*)(x + (size_t)t * D_))[tid];

    float s = v.x + v.y + v.z + v.w;
    #pragma unroll
    for (int off = 32; off > 0; off >>= 1) s += __shfl_down(s, off, 64);
    __shared__ float red[4];
    int wid = tid >> 6, lane = tid & 63;
    if (lane == 0) red[wid] = s;
    __syncthreads();
    float mu = (red[0] + red[1] + red[2] + red[3]) * (1.0f / D_);
    __syncthreads();

    float dx = v.x - mu, dy = v.y - mu, dz = v.z - mu, dw = v.w - mu;
    float ss = dx * dx + dy * dy + dz * dz + dw * dw;
    #pragma unroll
    for (int off = 32; off > 0; off >>= 1) ss += __shfl_down(ss, off, 64);
    if (lane == 0) red[wid] = ss;
    __syncthreads();
    float var = (red[0] + red[1] + red[2] + red[3]) * (1.0f / D_);
    float rs = rsqrtf(var + LN_EPS);

    const float4 g = ((const float4*)gamma)[tid];
    const float4 b = ((const float4*)beta)[tid];
    us4 o;
    o.x = f2bf(dx * rs * g.x + b.x);
    o.y = f2bf(dy * rs * g.y + b.y);
    o.z = f2bf(dz * rs * g.z + b.z);
    o.w = f2bf(dw * rs * g.w + b.w);
    ((us4*)(nb + (size_t)t * D_))[tid] = o;
}

// ---------------- K1b: W_enc fp32 -> bf16 ----------------
__global__ __launch_bounds__(256) void cvt_kernel(const float* __restrict__ W,
                                                  unsigned short* __restrict__ Wb) {
    const int tid = threadIdx.x;
    const size_t base = (size_t)blockIdx.x * 1024;
    #pragma unroll
    for (int j = 0; j < 4; j++) {
        size_t i = base + j * 256 + tid;
        float4 f = ((const float4*)W)[i];
        us4 o;
        o.x = f2bf(f.x); o.y = f2bf(f.y); o.z = f2bf(f.z); o.w = f2bf(f.w);
        ((us4*)Wb)[i] = o;
    }
}

// ---------------- K2: 256x256 bf16 MFMA GEMM + fused per-row top-6 candidates ----------------
// 512 threads = 8 waves (2M x 4N). Wave tile 128x64 (8x4 16x16 frags). BK=64.
// LDS: 2 buffers x (A 256x64 + B 256x64) bf16 = 128 KiB, 3-bit XOR swizzle.
// Epilogue reuses the LDS to stage fp32 C-quadrants and select per-token top-6
// candidates per 256-col block. NOTE: the quadrant loop MUST be fully unrolled
// so all acc[] indices are compile-time (rule #20: runtime-indexed ext_vector
// arrays demote the whole accumulator to scratch -- round-7 regression).
__global__ __launch_bounds__(512, 1) void gemm_kernel(const unsigned short* __restrict__ A,
                                                      const unsigned short* __restrict__ B,
                                                      float* __restrict__ cbv,
                                                      int* __restrict__ cbi) {
    __shared__ unsigned short lds[2][2][256][64];
    const int tid = threadIdx.x;
    const int lane = tid & 63;
    const int w = tid >> 6;
    const int wm = w >> 2, wn = w & 3;
    const int col0 = blockIdx.x * 256;   // dict cols
    const int row0 = blockIdx.y * 256;   // token rows

    f32x4 acc[8][4] = {};

    // stage one 128-row half (16KB = 1024 chunks of 16B): 2 chunks/thread.
    auto stage = [&](int b, int mat, const unsigned short* __restrict__ G,
                     int rbase, int k0, int h) {
        unsigned short* plane = &lds[b][mat][0][0];
        #pragma unroll
        for (int i = 0; i < 2; i++) {
            const int cb = h * 1024 + i * 512 + w * 64;   // wave-uniform chunk base
            const int c = cb + lane;
            const int r = c >> 3, sl = c & 7, g = sl ^ (r & 7);
            gl2lds16(G + (size_t)(rbase + r) * 1024 + k0 + g * 8, plane + (size_t)cb * 8);
        }
    };

    // prologue: stage tile 0 into buf 0
    stage(0, 0, A, row0, 0, 0);
    stage(0, 0, A, row0, 0, 1);
    stage(0, 1, B, col0, 0, 0);
    stage(0, 1, B, col0, 0, 1);

    const int arow = wm * 128 + (lane & 15);
    const int brow = wn * 64 + (lane & 15);
    const int kg = lane >> 4;

    for (int t = 0; t < 16; t++) {
        const int cur = t & 1, nxt = cur ^ 1;
        const int kn = ((t + 1) & 15) * 64;   // wrap-around keeps loop uniform

        // ---- phase 0: issue next A halves; wait tile t (leave 4 in flight); kk0, n={0,1}
        stage(nxt, 0, A, row0, kn, 0);
        stage(nxt, 0, A, row0, kn, 1);
        asm volatile("s_waitcnt vmcnt(4)" ::: "memory");
        __builtin_amdgcn_s_barrier();
        __builtin_amdgcn_sched_barrier(0);
        asm volatile("" ::: "memory");

        bf16x8 af[8];
        #pragma unroll
        for (int m = 0; m < 8; m++) {
            const int r = arow + m * 16;
            af[m] = *(const bf16x8*)&lds[cur][0][r][(kg ^ (r & 7)) * 8];
        }
        bf16x8 b0, b1;
        { const int r = brow;      b0 = *(const bf16x8*)&lds[cur][1][r][(kg ^ (r & 7)) * 8]; }
        { const int r = brow + 16; b1 = *(const bf16x8*)&lds[cur][1][r][(kg ^ (r & 7)) * 8]; }
        __builtin_amdgcn_s_setprio(1);
        #pragma unroll
        for (int m = 0; m < 8; m++) {
            acc[m][0] = __builtin_amdgcn_mfma_f32_16x16x32_bf16(af[m], b0, acc[m][0], 0, 0, 0);
            acc[m][1] = __builtin_amdgcn_mfma_f32_16x16x32_bf16(af[m], b1, acc[m][1], 0, 0, 0);
        }
        __builtin_amdgcn_s_setprio(0);

        // ---- phase 1: issue next B halves; kk0, n={2,3}
        stage(nxt, 1, B, col0, kn, 0);
        stage(nxt, 1, B, col0, kn, 1);
        { const int r = brow + 32; b0 = *(const bf16x8*)&lds[cur][1][r][(kg ^ (r & 7)) * 8]; }
        { const int r = brow + 48; b1 = *(const bf16x8*)&lds[cur][1][r][(kg ^ (r & 7)) * 8]; }
        __builtin_amdgcn_s_setprio(1);
        #pragma unroll
        for (int m = 0; m < 8; m++) {
            acc[m][2] = __builtin_amdgcn_mfma_f32_16x16x32_bf16(af[m], b0, acc[m][2], 0, 0, 0);
            acc[m][3] = __builtin_amdgcn_mfma_f32_16x16x32_bf16(af[m], b1, acc[m][3], 0, 0, 0);
        }
        __builtin_amdgcn_s_setprio(0);

        // ---- phase 2: kk1, n={0,1}
        #pragma unroll
        for (int m = 0; m < 8; m++) {
            const int r = arow + m * 16;
            af[m] = *(const bf16x8*)&lds[cur][0][r][((4 + kg) ^ (r & 7)) * 8];
        }
        { const int r = brow;      b0 = *(const bf16x8*)&lds[cur][1][r][((4 + kg) ^ (r & 7)) * 8]; }
        { const int r = brow + 16; b1 = *(const bf16x8*)&lds[cur][1][r][((4 + kg) ^ (r & 7)) * 8]; }
        __builtin_amdgcn_s_setprio(1);
        #pragma unroll
        for (int m = 0; m < 8; m++) {
            acc[m][0] = __builtin_amdgcn_mfma_f32_16x16x32_bf16(af[m], b0, acc[m][0], 0, 0, 0);
            acc[m][1] = __builtin_amdgcn_mfma_f32_16x16x32_bf16(af[m], b1, acc[m][1], 0, 0, 0);
        }
        __builtin_amdgcn_s_setprio(0);

        // ---- phase 3: kk1, n={2,3}
        { const int r = brow + 32; b0 = *(const bf16x8*)&lds[cur][1][r][((4 + kg) ^ (r & 7)) * 8]; }
        { const int r = brow + 48; b1 = *(const bf16x8*)&lds[cur][1][r][((4 + kg) ^ (r & 7)) * 8]; }
        __builtin_amdgcn_s_setprio(1);
        #pragma unroll
        for (int m = 0; m < 8; m++) {
            acc[m][2] = __builtin_amdgcn_mfma_f32_16x16x32_bf16(af[m], b0, acc[m][2], 0, 0, 0);
            acc[m][3] = __builtin_amdgcn_mfma_f32_16x16x32_bf16(af[m], b1, acc[m][3], 0, 0, 0);
        }
        __builtin_amdgcn_s_setprio(0);

        __builtin_amdgcn_s_barrier();
        __builtin_amdgcn_sched_barrier(0);
        asm volatile("" ::: "memory");
    }

    // ---- epilogue: drain in-flight wrap-around DMA before reusing LDS! ----
    asm volatile("s_waitcnt vmcnt(0)" ::: "memory");
    __builtin_amdgcn_s_barrier();
    __builtin_amdgcn_sched_barrier(0);

    // LDS reuse: sf = [64][260] f32 staging (padded rows), mv/mi = [64][49] merge scratch
    float* sf = (float*)&lds[0][0][0][0];
    float* mv = sf + 64 * 260;            // 16640 floats
    int*   mi = (int*)(mv + 64 * 49);     // +3136
    // total 22912 floats = 91.6 KB < 128 KB

    #pragma unroll
    for (int p = 0; p < 4; p++) {          // MUST be fully unrolled: acc indices static
        // stage 64-row quadrant p (rows p*64 .. p*64+63) as fp32
        if (wm == (p >> 1)) {
            const int mb = (p & 1) * 4;
            #pragma unroll
            for (int mm = 0; mm < 4; mm++) {
                #pragma unroll
                for (int n = 0; n < 4; n++) {
                    #pragma unroll
                    for (int r = 0; r < 4; r++) {
                        const int lrow = mm * 16 + (lane >> 4) * 4 + r;
                        sf[lrow * 260 + wn * 64 + n * 16 + (lane & 15)] = acc[mb + mm][n][r];
                    }
                }
            }
        }
        __syncthreads();

        // scan: 8 threads per row, stride-8 columns, per-thread top-6 insertion list
        {
            const int lr = tid >> 3, c8 = tid & 7;
            float v[CPB]; int id[CPB];
            #pragma unroll
            for (int j = 0; j < CPB; j++) { v[j] = -FLT_MAX; id[j] = -1; }
            #pragma unroll 4
            for (int k = 0; k < 32; k++) {
                const int col = c8 + k * 8;
                const float f = sf[lr * 260 + col];
                if (f > v[CPB - 1]) {
                    v[CPB - 1] = f; id[CPB - 1] = col0 + col;
                    #pragma unroll
                    for (int q = CPB - 1; q > 0; q--) {
                        if (v[q] > v[q - 1]) {
                            float tf = v[q]; v[q] = v[q - 1]; v[q - 1] = tf;
                            int ti = id[q]; id[q] = id[q - 1]; id[q - 1] = ti;
                        }
                    }
                }
            }
            const int mb2 = lr * 49 + c8 * CPB;
            #pragma unroll
            for (int j = 0; j < CPB; j++) { mv[mb2 + j] = v[j]; mi[mb2 + j] = id[j]; }
        }
        __syncthreads();

        // merge 48 -> top-6 per row; write candidates
        if (tid < 64) {
            float v[CPB]; int id[CPB];
            #pragma unroll
            for (int j = 0; j < CPB; j++) { v[j] = -FLT_MAX; id[j] = -1; }
            #pragma unroll 1
            for (int s = 0; s < 48; s++) {
                const float f = mv[tid * 49 + s];
                const int ii = mi[tid * 49 + s];
                if (f > v[CPB - 1]) {
                    v[CPB - 1] = f; id[CPB - 1] = ii;
                    #pragma unroll
                    for (int q = CPB - 1; q > 0; q--) {
                        if (v[q] > v[q - 1]) {
                            float tf = v[q]; v[q] = v[q - 1]; v[q - 1] = tf;
                            int ti = id[q]; id[q] = id[q - 1]; id[q - 1] = ti;
                        }
                    }
                }
            }
            const int token = row0 + p * 64 + tid;
            const size_t cb = ((size_t)token * NBLK + blockIdx.x) * CPB;
            #pragma unroll
            for (int j = 0; j < CPB; j++) { cbv[cb + j] = v[j]; cbi[cb + j] = id[j]; }
        }
        __syncthreads();
    }
}

// ---------------- K3: merge 64x6 block candidates -> top-12 per token ----------------
__global__ __launch_bounds__(256) void cand_merge_kernel(const float* __restrict__ cbv,
                                                         const int* __restrict__ cbi,
                                                         int* __restrict__ cand) {
    const int token = blockIdx.x;
    const int tid = threadIdx.x;
    const size_t base = (size_t)token * (NBLK * CPB);   // 384 items

    float a0 = cbv[base + tid];
    int j0 = cbi[base + tid];
    float a1 = -FLT_MAX;
    int j1 = -1;
    if (tid < 128) {
        a1 = cbv[base + 256 + tid];
        j1 = cbi[base + 256 + tid];
        if (a1 > a0) { float tf = a0; a0 = a1; a1 = tf; int ti = j0; j0 = j1; j1 = ti; }
    }

    __shared__ float hv[256];
    __shared__ int hi[256];
    __shared__ int wt;
    hv[tid] = a0;
    hi[tid] = j0;
    int myp = 0;

    for (int round = 0; round < NCAND; round++) {
        __syncthreads();
        if (tid < 64) {
            float bv = hv[tid]; int bt = tid;
            #pragma unroll
            for (int q = 1; q < 4; q++) {
                const int t2 = tid + q * 64;
                const float v2 = hv[t2];
                if (v2 > bv || (v2 == bv && t2 < bt)) { bv = v2; bt = t2; }
            }
            #pragma unroll
            for (int off = 32; off > 0; off >>= 1) {
                const float ov = __shfl_down(bv, off, 64);
                const int ot = __shfl_down(bt, off, 64);
                if (ov > bv || (ov == bv && ot < bt)) { bv = ov; bt = ot; }
            }
            if (tid == 0) wt = bt;
        }
        __syncthreads();
        if (tid == wt) {
            cand[(size_t)token * NCAND + round] = hi[tid];
            myp++;
            if (myp == 1) { hv[tid] = a1; hi[tid] = j1; }
            else { hv[tid] = -FLT_MAX; hi[tid] = -1; }
        }
    }
}

// ---------------- K4: exact fp32 refine of 12 candidates -> top-8 sel ----------------
__global__ __launch_bounds__(256) void refine_kernel(const float* __restrict__ x,
                                                     const float* __restrict__ gamma,
                                                     const float* __restrict__ beta,
                                                     const float* __restrict__ Wenc,
                                                     const int* __restrict__ cand,
                                                     float* __restrict__ sel_val,
                                                     int* __restrict__ sel_idx) {
    const int token = blockIdx.x;
    const int tid = threadIdx.x;
    const int lane = tid & 63;
    const int w = tid >> 6;

    __shared__ float red[4];
    __shared__ float ln[D_];

    const float4 v = ((const float4*)(x + (size_t)token * D_))[tid];
    float s = v.x + v.y + v.z + v.w;
    #pragma unroll
    for (int off = 32; off > 0; off >>= 1) s += __shfl_down(s, off, 64);
    if (lane == 0) red[w] = s;
    __syncthreads();
    float mu = (red[0] + red[1] + red[2] + red[3]) * (1.0f / D_);
    __syncthreads();
    float dx = v.x - mu, dy = v.y - mu, dz = v.z - mu, dw = v.w - mu;
    float ss = dx * dx + dy * dy + dz * dz + dw * dw;
    #pragma unroll
    for (int off = 32; off > 0; off >>= 1) ss += __shfl_down(ss, off, 64);
    if (lane == 0) red[w] = ss;
    __syncthreads();
    float var = (red[0] + red[1] + red[2] + red[3]) * (1.0f / D_);
    float rs = rsqrtf(var + LN_EPS);
    const float4 g = ((const float4*)gamma)[tid];
    const float4 b = ((const float4*)beta)[tid];
    float4 o;
    o.x = dx * rs * g.x + b.x;
    o.y = dy * rs * g.y + b.y;
    o.z = dz * rs * g.z + b.z;
    o.w = dw * rs * g.w + b.w;
    ((float4*)ln)[tid] = o;
    __syncthreads();

    __shared__ float dv[NCAND];
    __shared__ int di_s[NCAND];
    for (int c = w; c < NCAND; c += 4) {
        const int di = cand[(size_t)token * NCAND + c];
        const float4* wr = (const float4*)(Wenc + (size_t)di * D_);
        float acc = 0.f;
        #pragma unroll
        for (int j = 0; j < 4; j++) {
            const float4 q = wr[j * 64 + lane];
            const float4 p = ((const float4*)ln)[j * 64 + lane];
            acc += q.x * p.x + q.y * p.y + q.z * p.z + q.w * p.w;
        }
        #pragma unroll
        for (int off = 32; off > 0; off >>= 1) acc += __shfl_down(acc, off, 64);
        if (lane == 0) { dv[c] = acc; di_s[c] = di; }
    }
    __syncthreads();

    __shared__ float wv[TOPK];
    __shared__ int wi[TOPK];
    if (tid == 0) {
        unsigned int used = 0;
        for (int p = 0; p < TOPK; p++) {
            float bv = -FLT_MAX; int bc = -1;
            for (int c = 0; c < NCAND; c++) {
                if (used & (1u << c)) continue;
                const float cv = dv[c];
                if (cv > bv || (cv == bv && di_s[c] < ((bc >= 0) ? di_s[bc] : 0x7fffffff))) { bv = cv; bc = c; }
            }
            used |= 1u << bc;
            wv[p] = dv[bc]; wi[p] = di_s[bc];
        }
    }
    __syncthreads();
    if (tid < TOPK) {
        sel_val[(size_t)token * TOPK + tid] = wv[tid];
        sel_idx[(size_t)token * TOPK + tid] = wi[tid];
    }
}

// ---------------- K5: fused sparse-row writer + reconstruction ----------------
__global__ __launch_bounds__(256) void sparse_recon_kernel(const float* __restrict__ sel_val,
                                                           const int* __restrict__ sel_idx,
                                                           const float* __restrict__ Wdict,
                                                           float* __restrict__ sparse,
                                                           float* __restrict__ recon) {
    const int token = blockIdx.x;
    const int tid = threadIdx.x;
    __shared__ float v8[TOPK];
    __shared__ int i8[TOPK];
    if (tid < TOPK) {
        v8[tid] = sel_val[(size_t)token * TOPK + tid];
        i8[tid] = sel_idx[(size_t)token * TOPK + tid];
    }
    __syncthreads();

    // issue recon loads early (latency hides under the store stream)
    float4 wr[TOPK];
    #pragma unroll
    for (int j = 0; j < TOPK; j++)
        wr[j] = ((const float4*)(Wdict + (size_t)i8[j] * D_))[tid];

    f32x4* row = (f32x4*)(sparse + (size_t)token * DICT_);
    #pragma unroll
    for (int q = 0; q < 16; q++) {
        const int grp = q * 256 + tid;       // 4096 groups: full row
        const int base = grp * 4;
        f32x4 o = {0.f, 0.f, 0.f, 0.f};
        #pragma unroll
        for (int j = 0; j < TOPK; j++) {
            const int rel = i8[j] - base;
            o.x = (rel == 0) ? v8[j] : o.x;
            o.y = (rel == 1) ? v8[j] : o.y;
            o.z = (rel == 2) ? v8[j] : o.z;
            o.w = (rel == 3) ? v8[j] : o.w;
        }
        __builtin_nontemporal_store(o, row + grp);
    }

    float4 acc = {0.f, 0.f, 0.f, 0.f};
    #pragma unroll
    for (int j = 0; j < TOPK; j++) {
        const float c = v8[j];
        acc.x = fmaf(c, wr[j].x, acc.x);
        acc.y = fmaf(c, wr[j].y, acc.y);
        acc.z = fmaf(c, wr[j].z, acc.z);
        acc.w = fmaf(c, wr[j].w, acc.w);
    }
    ((float4*)(recon + (size_t)token * D_))[tid] = acc;
}

extern "C" void kernel_launch(void* const* d_in, const int* in_sizes, int n_in,
                              void* d_out, int out_size, void* d_ws, size_t ws_size,
                              hipStream_t stream) {
    const float* x = (const float*)d_in[0];
    const float* gamma = (const float*)d_in[1];
    const float* beta = (const float*)d_in[2];
    const float* Wenc = (const float*)d_in[3];
    const float* Wdict = (const float*)d_in[4];

    float* recon = (float*)d_out;
    float* sparse = (float*)d_out + (size_t)NTOK * D_;

    // scratch in d_ws (~55 MB)
    unsigned short* We = (unsigned short*)d_ws;                   // bf16 W_enc, 33.5 MB
    unsigned short* Nb = We + (size_t)DICT_ * D_;                 // bf16 normed, 8 MB
    float* cbv = (float*)(Nb + (size_t)NTOK * D_);                // 4096*64*6 f32
    int* cbi = (int*)(cbv + (size_t)NTOK * NBLK * CPB);           // 4096*64*6 int
    int* cand = cbi + (size_t)NTOK * NBLK * CPB;                  // 4096*12 int
    float* sel_val = (float*)(cand + (size_t)NTOK * NCAND);       // 4096*8 f32
    int* sel_idx = (int*)(sel_val + (size_t)NTOK * TOPK);         // 4096*8 int

    ln_kernel<<<NTOK, 256, 0, stream>>>(x, gamma, beta, Nb);
    cvt_kernel<<<DICT_ * D_ / 4096, 256, 0, stream>>>(Wenc, We);

    dim3 gg(DICT_ / 256, NTOK / 256);
    gemm_kernel<<<gg, 512, 0, stream>>>(Nb, We, cbv, cbi);

    cand_merge_kernel<<<NTOK, 256, 0, stream>>>(cbv, cbi, cand);

    refine_kernel<<<NTOK, 256, 0, stream>>>(x, gamma, beta, Wenc, cand,
                                            sel_val, sel_idx);

    sparse_recon_kernel<<<NTOK, 256, 0, stream>>>(sel_val, sel_idx, Wdict,
                                                  sparse, recon);
}

// Round 9
// 309.619 us; speedup vs baseline: 1.8993x; 1.4503x over previous
//
#include <hip/hip_runtime.h>
#include <hip/hip_bf16.h>
#include <cfloat>

#define NTOK 4096
#define D_ 1024
#define DICT_ 16384
#define TOPK 8
#define NCAND 12
#define LN_EPS 1e-5f

typedef __attribute__((ext_vector_type(8))) short bf16x8;
typedef __attribute__((ext_vector_type(4))) float f32x4;
typedef __attribute__((ext_vector_type(8))) unsigned short us8;
typedef __attribute__((ext_vector_type(4))) unsigned short us4;

__device__ __forceinline__ unsigned short f2bf(float f) {
    unsigned int u = __float_as_uint(f);
    u += 0x7fffu + ((u >> 16) & 1u);   // RNE
    return (unsigned short)(u >> 16);
}
__device__ __forceinline__ float bf2f(unsigned short u) {
    return __uint_as_float(((unsigned int)u) << 16);
}

__device__ __forceinline__ void gl2lds16(const void* gsrc, void* ldsdst) {
    __builtin_amdgcn_global_load_lds(
        (const __attribute__((address_space(1))) unsigned int*)gsrc,
        (__attribute__((address_space(3))) unsigned int*)ldsdst, 16, 0, 0);
}

// ---------------- K1: LayerNorm -> bf16 normed ----------------
__global__ __launch_bounds__(256) void ln_kernel(const float* __restrict__ x,
                                                 const float* __restrict__ gamma,
                                                 const float* __restrict__ beta,
                                                 unsigned short* __restrict__ nb) {
    int t = blockIdx.x;
    int tid = threadIdx.x;
    const float4 v = ((const float4*)(x + (size_t)t * D_))[tid];

    float s = v.x + v.y + v.z + v.w;
    #pragma unroll
    for (int off = 32; off > 0; off >>= 1) s += __shfl_down(s, off, 64);
    __shared__ float red[4];
    int wid = tid >> 6, lane = tid & 63;
    if (lane == 0) red[wid] = s;
    __syncthreads();
    float mu = (red[0] + red[1] + red[2] + red[3]) * (1.0f / D_);
    __syncthreads();

    float dx = v.x - mu, dy = v.y - mu, dz = v.z - mu, dw = v.w - mu;
    float ss = dx * dx + dy * dy + dz * dz + dw * dw;
    #pragma unroll
    for (int off = 32; off > 0; off >>= 1) ss += __shfl_down(ss, off, 64);
    if (lane == 0) red[wid] = ss;
    __syncthreads();
    float var = (red[0] + red[1] + red[2] + red[3]) * (1.0f / D_);
    float rs = rsqrtf(var + LN_EPS);

    const float4 g = ((const float4*)gamma)[tid];
    const float4 b = ((const float4*)beta)[tid];
    us4 o;
    o.x = f2bf(dx * rs * g.x + b.x);
    o.y = f2bf(dy * rs * g.y + b.y);
    o.z = f2bf(dz * rs * g.z + b.z);
    o.w = f2bf(dw * rs * g.w + b.w);
    ((us4*)(nb + (size_t)t * D_))[tid] = o;
}

// ---------------- K1b: W_enc fp32 -> bf16 ----------------
__global__ __launch_bounds__(256) void cvt_kernel(const float* __restrict__ W,
                                                  unsigned short* __restrict__ Wb) {
    const int tid = threadIdx.x;
    const size_t base = (size_t)blockIdx.x * 1024;
    #pragma unroll
    for (int j = 0; j < 4; j++) {
        size_t i = base + j * 256 + tid;
        float4 f = ((const float4*)W)[i];
        us4 o;
        o.x = f2bf(f.x); o.y = f2bf(f.y); o.z = f2bf(f.z); o.w = f2bf(f.w);
        ((us4*)Wb)[i] = o;
    }
}

// ---------------- K2: 256x256 bf16 MFMA GEMM, counted-vmcnt phase schedule ----------------
// (known-good R6 version: writes bf16 logits; no fused epilogue)
__global__ __launch_bounds__(512, 1) void gemm_kernel(const unsigned short* __restrict__ A,
                                                      const unsigned short* __restrict__ B,
                                                      unsigned short* __restrict__ L) {
    __shared__ unsigned short lds[2][2][256][64];
    const int tid = threadIdx.x;
    const int lane = tid & 63;
    const int w = tid >> 6;
    const int wm = w >> 2, wn = w & 3;
    const int col0 = blockIdx.x * 256;   // dict cols
    const int row0 = blockIdx.y * 256;   // token rows

    f32x4 acc[8][4] = {};

    auto stage = [&](int b, int mat, const unsigned short* __restrict__ G,
                     int rbase, int k0, int h) {
        unsigned short* plane = &lds[b][mat][0][0];
        #pragma unroll
        for (int i = 0; i < 2; i++) {
            const int cb = h * 1024 + i * 512 + w * 64;   // wave-uniform chunk base
            const int c = cb + lane;
            const int r = c >> 3, sl = c & 7, g = sl ^ (r & 7);
            gl2lds16(G + (size_t)(rbase + r) * 1024 + k0 + g * 8, plane + (size_t)cb * 8);
        }
    };

    // prologue: stage tile 0 into buf 0
    stage(0, 0, A, row0, 0, 0);
    stage(0, 0, A, row0, 0, 1);
    stage(0, 1, B, col0, 0, 0);
    stage(0, 1, B, col0, 0, 1);

    const int arow = wm * 128 + (lane & 15);
    const int brow = wn * 64 + (lane & 15);
    const int kg = lane >> 4;

    for (int t = 0; t < 16; t++) {
        const int cur = t & 1, nxt = cur ^ 1;
        const int kn = ((t + 1) & 15) * 64;   // wrap-around keeps loop uniform

        // ---- phase 0: issue next A halves; wait tile t (leave 4 in flight); kk0, n={0,1}
        stage(nxt, 0, A, row0, kn, 0);
        stage(nxt, 0, A, row0, kn, 1);
        asm volatile("s_waitcnt vmcnt(4)" ::: "memory");
        __builtin_amdgcn_s_barrier();
        __builtin_amdgcn_sched_barrier(0);
        asm volatile("" ::: "memory");

        bf16x8 af[8];
        #pragma unroll
        for (int m = 0; m < 8; m++) {
            const int r = arow + m * 16;
            af[m] = *(const bf16x8*)&lds[cur][0][r][(kg ^ (r & 7)) * 8];
        }
        bf16x8 b0, b1;
        { const int r = brow;      b0 = *(const bf16x8*)&lds[cur][1][r][(kg ^ (r & 7)) * 8]; }
        { const int r = brow + 16; b1 = *(const bf16x8*)&lds[cur][1][r][(kg ^ (r & 7)) * 8]; }
        __builtin_amdgcn_s_setprio(1);
        #pragma unroll
        for (int m = 0; m < 8; m++) {
            acc[m][0] = __builtin_amdgcn_mfma_f32_16x16x32_bf16(af[m], b0, acc[m][0], 0, 0, 0);
            acc[m][1] = __builtin_amdgcn_mfma_f32_16x16x32_bf16(af[m], b1, acc[m][1], 0, 0, 0);
        }
        __builtin_amdgcn_s_setprio(0);

        // ---- phase 1: issue next B halves; kk0, n={2,3}
        stage(nxt, 1, B, col0, kn, 0);
        stage(nxt, 1, B, col0, kn, 1);
        { const int r = brow + 32; b0 = *(const bf16x8*)&lds[cur][1][r][(kg ^ (r & 7)) * 8]; }
        { const int r = brow + 48; b1 = *(const bf16x8*)&lds[cur][1][r][(kg ^ (r & 7)) * 8]; }
        __builtin_amdgcn_s_setprio(1);
        #pragma unroll
        for (int m = 0; m < 8; m++) {
            acc[m][2] = __builtin_amdgcn_mfma_f32_16x16x32_bf16(af[m], b0, acc[m][2], 0, 0, 0);
            acc[m][3] = __builtin_amdgcn_mfma_f32_16x16x32_bf16(af[m], b1, acc[m][3], 0, 0, 0);
        }
        __builtin_amdgcn_s_setprio(0);

        // ---- phase 2: kk1, n={0,1}
        #pragma unroll
        for (int m = 0; m < 8; m++) {
            const int r = arow + m * 16;
            af[m] = *(const bf16x8*)&lds[cur][0][r][((4 + kg) ^ (r & 7)) * 8];
        }
        { const int r = brow;      b0 = *(const bf16x8*)&lds[cur][1][r][((4 + kg) ^ (r & 7)) * 8]; }
        { const int r = brow + 16; b1 = *(const bf16x8*)&lds[cur][1][r][((4 + kg) ^ (r & 7)) * 8]; }
        __builtin_amdgcn_s_setprio(1);
        #pragma unroll
        for (int m = 0; m < 8; m++) {
            acc[m][0] = __builtin_amdgcn_mfma_f32_16x16x32_bf16(af[m], b0, acc[m][0], 0, 0, 0);
            acc[m][1] = __builtin_amdgcn_mfma_f32_16x16x32_bf16(af[m], b1, acc[m][1], 0, 0, 0);
        }
        __builtin_amdgcn_s_setprio(0);

        // ---- phase 3: kk1, n={2,3}
        { const int r = brow + 32; b0 = *(const bf16x8*)&lds[cur][1][r][((4 + kg) ^ (r & 7)) * 8]; }
        { const int r = brow + 48; b1 = *(const bf16x8*)&lds[cur][1][r][((4 + kg) ^ (r & 7)) * 8]; }
        __builtin_amdgcn_s_setprio(1);
        #pragma unroll
        for (int m = 0; m < 8; m++) {
            acc[m][2] = __builtin_amdgcn_mfma_f32_16x16x32_bf16(af[m], b0, acc[m][2], 0, 0, 0);
            acc[m][3] = __builtin_amdgcn_mfma_f32_16x16x32_bf16(af[m], b1, acc[m][3], 0, 0, 0);
        }
        __builtin_amdgcn_s_setprio(0);

        __builtin_amdgcn_s_barrier();
        __builtin_amdgcn_sched_barrier(0);
        asm volatile("" ::: "memory");
    }

    // epilogue: C/D layout col=lane&15, row=(lane>>4)*4+reg
    #pragma unroll
    for (int m = 0; m < 8; m++) {
        const int rb = row0 + wm * 128 + m * 16 + (lane >> 4) * 4;
        #pragma unroll
        for (int n = 0; n < 4; n++) {
            const int col = col0 + wn * 64 + n * 16 + (lane & 15);
            #pragma unroll
            for (int r = 0; r < 4; r++)
                L[(size_t)(rb + r) * DICT_ + col] = f2bf(acc[m][n][r]);
        }
    }
}

// ---------------- K3: per-token top-12 candidates from bf16 logits ----------------
__global__ __launch_bounds__(256) void cand_kernel(const unsigned short* __restrict__ L,
                                                   int* __restrict__ cand) {
    const int token = blockIdx.x;
    const int tid = threadIdx.x;
    const unsigned short* row = L + (size_t)token * DICT_;

    float v[5];
    int id[5];
    #pragma unroll
    for (int j = 0; j < 5; j++) { v[j] = -FLT_MAX; id[j] = -1; }

    for (int j = 0; j < 8; j++) {
        const int fi = j * 256 + tid;            // 16B group index (2048 per row)
        const us8 u = *(const us8*)&row[fi * 8];
        #pragma unroll
        for (int e = 0; e < 8; e++) {
            const float f = bf2f(u[e]);
            if (f > v[4]) {
                v[4] = f; id[4] = fi * 8 + e;
                #pragma unroll
                for (int q = 4; q > 0; q--) {
                    if (v[q] > v[q - 1]) {
                        float tv = v[q]; v[q] = v[q - 1]; v[q - 1] = tv;
                        int ti = id[q]; id[q] = id[q - 1]; id[q - 1] = ti;
                    }
                }
            }
        }
    }

    __shared__ float hv[256];
    __shared__ int hi[256];
    __shared__ int hp[256];
    __shared__ int wt;
    hv[tid] = v[0];
    hi[tid] = id[0];
    hp[tid] = 0;

    for (int round = 0; round < NCAND; round++) {
        __syncthreads();
        if (tid < 64) {
            float bv = hv[tid]; int bt = tid;
            #pragma unroll
            for (int q = 1; q < 4; q++) {
                const int t2 = tid + q * 64;
                const float v2 = hv[t2];
                if (v2 > bv || (v2 == bv && t2 < bt)) { bv = v2; bt = t2; }
            }
            #pragma unroll
            for (int off = 32; off > 0; off >>= 1) {
                const float ov = __shfl_down(bv, off, 64);
                const int ot = __shfl_down(bt, off, 64);
                if (ov > bv || (ov == bv && ot < bt)) { bv = ov; bt = ot; }
            }
            if (tid == 0) wt = bt;
        }
        __syncthreads();
        if (tid == wt) {
            cand[(size_t)token * NCAND + round] = hi[tid];
            const int p = hp[tid] + 1;
            hp[tid] = p;
            if (p < 5) { hv[tid] = v[p]; hi[tid] = id[p]; }
            else { hv[tid] = -FLT_MAX; hi[tid] = -1; }
        }
    }
}

// ---------------- K4: exact fp32 refine of 12 candidates -> top-8 sel ----------------
__global__ __launch_bounds__(256) void refine_kernel(const float* __restrict__ x,
                                                     const float* __restrict__ gamma,
                                                     const float* __restrict__ beta,
                                                     const float* __restrict__ Wenc,
                                                     const int* __restrict__ cand,
                                                     float* __restrict__ sel_val,
                                                     int* __restrict__ sel_idx) {
    const int token = blockIdx.x;
    const int tid = threadIdx.x;
    const int lane = tid & 63;
    const int w = tid >> 6;

    __shared__ float red[4];
    __shared__ float ln[D_];

    const float4 v = ((const float4*)(x + (size_t)token * D_))[tid];
    float s = v.x + v.y + v.z + v.w;
    #pragma unroll
    for (int off = 32; off > 0; off >>= 1) s += __shfl_down(s, off, 64);
    if (lane == 0) red[w] = s;
    __syncthreads();
    float mu = (red[0] + red[1] + red[2] + red[3]) * (1.0f / D_);
    __syncthreads();
    float dx = v.x - mu, dy = v.y - mu, dz = v.z - mu, dw = v.w - mu;
    float ss = dx * dx + dy * dy + dz * dz + dw * dw;
    #pragma unroll
    for (int off = 32; off > 0; off >>= 1) ss += __shfl_down(ss, off, 64);
    if (lane == 0) red[w] = ss;
    __syncthreads();
    float var = (red[0] + red[1] + red[2] + red[3]) * (1.0f / D_);
    float rs = rsqrtf(var + LN_EPS);
    const float4 g = ((const float4*)gamma)[tid];
    const float4 b = ((const float4*)beta)[tid];
    float4 o;
    o.x = dx * rs * g.x + b.x;
    o.y = dy * rs * g.y + b.y;
    o.z = dz * rs * g.z + b.z;
    o.w = dw * rs * g.w + b.w;
    ((float4*)ln)[tid] = o;
    __syncthreads();

    __shared__ float dv[NCAND];
    __shared__ int di_s[NCAND];
    for (int c = w; c < NCAND; c += 4) {
        const int di = cand[(size_t)token * NCAND + c];
        const float4* wr = (const float4*)(Wenc + (size_t)di * D_);
        float acc = 0.f;
        #pragma unroll
        for (int j = 0; j < 4; j++) {
            const float4 q = wr[j * 64 + lane];
            const float4 p = ((const float4*)ln)[j * 64 + lane];
            acc += q.x * p.x + q.y * p.y + q.z * p.z + q.w * p.w;
        }
        #pragma unroll
        for (int off = 32; off > 0; off >>= 1) acc += __shfl_down(acc, off, 64);
        if (lane == 0) { dv[c] = acc; di_s[c] = di; }
    }
    __syncthreads();

    __shared__ float wv[TOPK];
    __shared__ int wi[TOPK];
    if (tid == 0) {
        unsigned int used = 0;
        for (int p = 0; p < TOPK; p++) {
            float bv = -FLT_MAX; int bc = -1;
            for (int c = 0; c < NCAND; c++) {
                if (used & (1u << c)) continue;
                const float cv = dv[c];
                if (cv > bv || (cv == bv && di_s[c] < ((bc >= 0) ? di_s[bc] : 0x7fffffff))) { bv = cv; bc = c; }
            }
            used |= 1u << bc;
            wv[p] = dv[bc]; wi[p] = di_s[bc];
        }
    }
    __syncthreads();
    if (tid < TOPK) {
        sel_val[(size_t)token * TOPK + tid] = wv[tid];
        sel_idx[(size_t)token * TOPK + tid] = wi[tid];
    }
}

// ---------------- K5: fused sparse-row writer + reconstruction ----------------
__global__ __launch_bounds__(256) void sparse_recon_kernel(const float* __restrict__ sel_val,
                                                           const int* __restrict__ sel_idx,
                                                           const float* __restrict__ Wdict,
                                                           float* __restrict__ sparse,
                                                           float* __restrict__ recon) {
    const int token = blockIdx.x;
    const int tid = threadIdx.x;
    __shared__ float v8[TOPK];
    __shared__ int i8[TOPK];
    if (tid < TOPK) {
        v8[tid] = sel_val[(size_t)token * TOPK + tid];
        i8[tid] = sel_idx[(size_t)token * TOPK + tid];
    }
    __syncthreads();

    // issue recon loads early (latency hides under the store stream)
    float4 wr[TOPK];
    #pragma unroll
    for (int j = 0; j < TOPK; j++)
        wr[j] = ((const float4*)(Wdict + (size_t)i8[j] * D_))[tid];

    f32x4* row = (f32x4*)(sparse + (size_t)token * DICT_);
    #pragma unroll
    for (int q = 0; q < 16; q++) {
        const int grp = q * 256 + tid;       // 4096 groups: full row
        const int base = grp * 4;
        f32x4 o = {0.f, 0.f, 0.f, 0.f};
        #pragma unroll
        for (int j = 0; j < TOPK; j++) {
            const int rel = i8[j] - base;
            o.x = (rel == 0) ? v8[j] : o.x;
            o.y = (rel == 1) ? v8[j] : o.y;
            o.z = (rel == 2) ? v8[j] : o.z;
            o.w = (rel == 3) ? v8[j] : o.w;
        }
        __builtin_nontemporal_store(o, row + grp);
    }

    float4 acc = {0.f, 0.f, 0.f, 0.f};
    #pragma unroll
    for (int j = 0; j < TOPK; j++) {
        const float c = v8[j];
        acc.x = fmaf(c, wr[j].x, acc.x);
        acc.y = fmaf(c, wr[j].y, acc.y);
        acc.z = fmaf(c, wr[j].z, acc.z);
        acc.w = fmaf(c, wr[j].w, acc.w);
    }
    ((float4*)(recon + (size_t)token * D_))[tid] = acc;
}

extern "C" void kernel_launch(void* const* d_in, const int* in_sizes, int n_in,
                              void* d_out, int out_size, void* d_ws, size_t ws_size,
                              hipStream_t stream) {
    const float* x = (const float*)d_in[0];
    const float* gamma = (const float*)d_in[1];
    const float* beta = (const float*)d_in[2];
    const float* Wenc = (const float*)d_in[3];
    const float* Wdict = (const float*)d_in[4];

    float* recon = (float*)d_out;
    float* sparse = (float*)d_out + (size_t)NTOK * D_;

    // all scratch in d_ws (~176.5 MB)
    unsigned short* Lg = (unsigned short*)d_ws;                   // bf16 logits, 134 MB
    unsigned short* We = Lg + (size_t)NTOK * DICT_;               // bf16 W_enc, 33.5 MB
    unsigned short* Nb = We + (size_t)DICT_ * D_;                 // bf16 normed, 8 MB
    int* cand = (int*)(Nb + (size_t)NTOK * D_);                   // 4096*12 int
    float* sel_val = (float*)(cand + (size_t)NTOK * NCAND);       // 4096*8 f32
    int* sel_idx = (int*)(sel_val + (size_t)NTOK * TOPK);         // 4096*8 int

    ln_kernel<<<NTOK, 256, 0, stream>>>(x, gamma, beta, Nb);
    cvt_kernel<<<DICT_ * D_ / 4096, 256, 0, stream>>>(Wenc, We);

    dim3 gg(DICT_ / 256, NTOK / 256);
    gemm_kernel<<<gg, 512, 0, stream>>>(Nb, We, Lg);

    cand_kernel<<<NTOK, 256, 0, stream>>>(Lg, cand);

    refine_kernel<<<NTOK, 256, 0, stream>>>(x, gamma, beta, Wenc, cand,
                                            sel_val, sel_idx);

    sparse_recon_kernel<<<NTOK, 256, 0, stream>>>(sel_val, sel_idx, Wdict,
                                                  sparse, recon);
}